// Round 2
// baseline (660.539 us; speedup 1.0000x reference)
//
#include <hip/hip_runtime.h>
#include <cstdint>

// LCA model constants
#define T_STEPS 3000
#define S_SIMS  1000
#define D_DIM   16
#define NJ      (S_SIMS * D_DIM)          // 16000 elements per step
#define ROW     (T_STEPS + 1)             // 3001 outputs per (s,d)
#define HALF_OUT ((long long)NJ * ROW)    // 48,016,000 floats per output tensor

// JAX RNG variant: 1 = threefry_partitionable (default in modern JAX), 0 = original
#define PARTITIONABLE 1

__device__ uint2 g_keys[T_STEPS];
__device__ float g_noise[(size_t)T_STEPS * NJ];   // [t][j] layout, j = s*16+d

// ---------------------------------------------------------------------------
// Threefry-2x32 (20 rounds), bit-exact vs jax._src.prng
// ---------------------------------------------------------------------------
__device__ __forceinline__ uint32_t rotl32(uint32_t v, uint32_t d) {
  return (v << d) | (v >> (32u - d));
}

__device__ __forceinline__ void threefry2x32(uint32_t k0, uint32_t k1,
                                             uint32_t& x0, uint32_t& x1) {
  uint32_t k2 = k0 ^ k1 ^ 0x1BD11BDAu;
  x0 += k0; x1 += k1;
#define TFR(r) { x0 += x1; x1 = rotl32(x1, r); x1 ^= x0; }
  TFR(13u) TFR(15u) TFR(26u) TFR(6u)
  x0 += k1; x1 += k2 + 1u;
  TFR(17u) TFR(29u) TFR(16u) TFR(24u)
  x0 += k2; x1 += k0 + 2u;
  TFR(13u) TFR(15u) TFR(26u) TFR(6u)
  x0 += k0; x1 += k1 + 3u;
  TFR(17u) TFR(29u) TFR(16u) TFR(24u)
  x0 += k1; x1 += k2 + 4u;
  TFR(13u) TFR(15u) TFR(26u) TFR(6u)
  x0 += k2; x1 += k0 + 5u;
#undef TFR
}

// ---------------------------------------------------------------------------
// bits -> N(0,1) float, matching jax.random.normal f32 path:
//   u = max(lo, u01*2.0f + lo), lo = nextafter(-1,0); n = sqrt2 * erfinv(u)
// erfinv = XLA ErfInv32 (Giles) polynomial.
// ---------------------------------------------------------------------------
__device__ __forceinline__ float bits_to_normal(uint32_t bits) {
  uint32_t fb = (bits >> 9) | 0x3f800000u;
  float f = __uint_as_float(fb) - 1.0f;        // [0, 1)
  const float lo = -0.99999994f;               // nextafter(-1,0) in f32
  float u = f * 2.0f + lo;                     // (maxval - minval) == 2.0f exactly
  u = fmaxf(lo, u);

  float w = -log1pf(-u * u);
  float p;
  if (w < 5.0f) {
    w = w - 2.5f;
    p = 2.81022636e-08f;
    p = fmaf(p, w, 3.43273939e-07f);
    p = fmaf(p, w, -3.5233877e-06f);
    p = fmaf(p, w, -4.39150654e-06f);
    p = fmaf(p, w, 0.00021858087f);
    p = fmaf(p, w, -0.00125372503f);
    p = fmaf(p, w, -0.00417768164f);
    p = fmaf(p, w, 0.246640727f);
    p = fmaf(p, w, 1.50140941f);
  } else {
    w = sqrtf(w) - 3.0f;
    p = -0.000200214257f;
    p = fmaf(p, w, 0.000100950558f);
    p = fmaf(p, w, 0.00134934322f);
    p = fmaf(p, w, -0.00367342844f);
    p = fmaf(p, w, 0.00573950773f);
    p = fmaf(p, w, -0.0076224613f);
    p = fmaf(p, w, 0.00943887047f);
    p = fmaf(p, w, 1.00167406f);
    p = fmaf(p, w, 2.83297682f);
  }
  return 1.41421356237f * (p * u);
}

// ---------------------------------------------------------------------------
// K0: per-step keys from jax.random.split(key(42), T)
// ---------------------------------------------------------------------------
__global__ void keys_kernel() {
  int t = blockIdx.x * blockDim.x + threadIdx.x;
  if (t >= T_STEPS) return;
#if PARTITIONABLE
  // foldlike split: key_t = threefry2x32((0,42), (hi32(t)=0, lo32(t)=t))
  uint32_t x0 = 0u, x1 = (uint32_t)t;
  threefry2x32(0u, 42u, x0, x1);
  g_keys[t] = make_uint2(x0, x1);
#else
  // original split: counts = iota(2T); pairs (i, i+T); out = concat(y0, y1)
  // keys[t] = (out[2t], out[2t+1])
  uint32_t i0, i1; bool second;
  if (t < T_STEPS / 2) { i0 = 2u * t;           i1 = 2u * t + 1u;           second = false; }
  else                 { i0 = 2u * t - T_STEPS; i1 = 2u * t - T_STEPS + 1u; second = true;  }
  uint32_t a0 = i0, a1 = i0 + T_STEPS;
  threefry2x32(0u, 42u, a0, a1);
  uint32_t b0 = i1, b1 = i1 + T_STEPS;
  threefry2x32(0u, 42u, b0, b1);
  g_keys[t] = second ? make_uint2(a1, b1) : make_uint2(a0, b0);
#endif
}

// ---------------------------------------------------------------------------
// KA: all normals for all steps, fully parallel.
// ---------------------------------------------------------------------------
#if PARTITIONABLE
__global__ __launch_bounds__(256) void noise_kernel() {
  int j = blockIdx.x * blockDim.x + threadIdx.x;
  if (j >= NJ) return;
  int t = blockIdx.y;
  uint2 k = g_keys[t];
  // bits[j] = xor(threefry(key_t, (0, j)))
  uint32_t x0 = 0u, x1 = (uint32_t)j;
  threefry2x32(k.x, k.y, x0, x1);
  g_noise[t * NJ + j] = bits_to_normal(x0 ^ x1);
}
#else
__global__ __launch_bounds__(256) void noise_kernel() {
  int j = blockIdx.x * blockDim.x + threadIdx.x;   // pair index, 0..NJ/2-1
  if (j >= NJ / 2) return;
  int t = blockIdx.y;
  uint2 k = g_keys[t];
  uint32_t x0 = (uint32_t)j, x1 = (uint32_t)(j + NJ / 2);
  threefry2x32(k.x, k.y, x0, x1);
  g_noise[t * NJ + j]          = bits_to_normal(x0);
  g_noise[t * NJ + j + NJ / 2] = bits_to_normal(x1);
}
#endif

// ---------------------------------------------------------------------------
// KB: sequential LCA dynamics. 16 lanes per simulation (d = lane&15),
// 4 sims per wave64, 250 blocks x 64 threads. Early exit on absorption,
// float4 tail fill.
// ---------------------------------------------------------------------------
__global__ __launch_bounds__(64) void sim_kernel(const float* __restrict__ ff,
                                                 float* __restrict__ out) {
  const int j = blockIdx.x * 64 + threadIdx.x;     // 0..15999  (s = j>>4, d = j&15)
  const float ffv = ff[j];
  float* __restrict__ pre_out = out + (long long)j * ROW;
  float* __restrict__ act_out = out + HALF_OUT + (long long)j * ROW;
  pre_out[0] = 0.0f;
  act_out[0] = 0.0f;

  float pre = 0.0f, act = 0.0f;
  int tfreeze = T_STEPS;

  float nbuf[4], nnxt[4];
#pragma unroll
  for (int k = 0; k < 4; ++k) nbuf[k] = g_noise[k * NJ + j];

  for (int t0 = 0; t0 < T_STEPS; t0 += 4) {
    if (t0 + 4 < T_STEPS) {
#pragma unroll
      for (int k = 0; k < 4; ++k) nnxt[k] = g_noise[(t0 + 4 + k) * NJ + j];
    }
#pragma unroll
    for (int k = 0; k < 4; ++k) {
      // 16-lane butterfly: sum(act) and max(act) (act >= 0, so |act| = act)
      float s = act, m = act;
#pragma unroll
      for (int msk = 1; msk <= 8; msk <<= 1) {
        s += __shfl_xor(s, msk, 16);
        m = fmaxf(m, __shfl_xor(m, msk, 16));
      }
      if (tfreeze == T_STEPS) {
        if (!(m < 1.0f)) {
          tfreeze = t0 + k;        // this and all later outputs are frozen
        } else {
          // pre += (ff - leak*pre - act@gamma) * dt ; gamma => 0.1*(rowsum - act_d)
          float expr = ffv - 0.1f * pre - 0.1f * (s - act);
          pre = pre + expr * 0.01f;
          pre = pre + nbuf[k] * 0.03162277660168379f;   // + dw * sqrt(0.001)
          act = fmaxf(pre, 0.0f);
          pre_out[t0 + k + 1] = pre;
          act_out[t0 + k + 1] = act;
        }
      }
    }
    if (tfreeze != T_STEPS) break;
#pragma unroll
    for (int k = 0; k < 4; ++k) nbuf[k] = nnxt[k];
  }

  // Fill frozen tail: columns [tfreeze+1 .. 3000] = current (pre, act)
  int idx = tfreeze + 1;
  if (idx <= T_STEPS) {
    while (idx <= T_STEPS && (((unsigned)(j * ROW + idx)) & 3u)) {
      pre_out[idx] = pre; act_out[idx] = act; ++idx;
    }
    float4 pv = make_float4(pre, pre, pre, pre);
    float4 av = make_float4(act, act, act, act);
    for (; idx + 4 <= ROW; idx += 4) {
      *reinterpret_cast<float4*>(pre_out + idx) = pv;
      *reinterpret_cast<float4*>(act_out + idx) = av;
    }
    for (; idx <= T_STEPS; ++idx) { pre_out[idx] = pre; act_out[idx] = act; }
  }
}

// ---------------------------------------------------------------------------
extern "C" void kernel_launch(void* const* d_in, const int* in_sizes, int n_in,
                              void* d_out, int out_size, void* d_ws, size_t ws_size,
                              hipStream_t stream) {
  const float* ff = (const float*)d_in[0];
  float* out = (float*)d_out;

  keys_kernel<<<dim3((T_STEPS + 255) / 256), dim3(256), 0, stream>>>();
#if PARTITIONABLE
  noise_kernel<<<dim3((NJ + 255) / 256, T_STEPS), dim3(256), 0, stream>>>();
#else
  noise_kernel<<<dim3((NJ / 2 + 255) / 256, T_STEPS), dim3(256), 0, stream>>>();
#endif
  sim_kernel<<<dim3(NJ / 64), dim3(64), 0, stream>>>(ff, out);
}

// Round 4
// 342.721 us; speedup vs baseline: 1.9273x; 1.9273x over previous
//
#include <hip/hip_runtime.h>
#include <cstdint>

// LCA model constants
#define T_STEPS 3000
#define S_SIMS  1000
#define D_DIM   16
#define NJ      (S_SIMS * D_DIM)          // 16000 elements per step
#define ROW     (T_STEPS + 1)             // 3001 outputs per (s,d)
#define HALF_OUT ((long long)NJ * ROW)    // 48,016,000 floats per output tensor

#define USE_DPP 1

__device__ uint2  g_keys[T_STEPS];
__device__ int    g_tf[S_SIMS];
__device__ float  g_ws_pre[(size_t)T_STEPS * NJ];   // [t][j], j = s*16+d; prefix only

// ---------------------------------------------------------------------------
// Threefry-2x32 (20 rounds), bit-exact vs jax._src.prng (partitionable mode)
// ---------------------------------------------------------------------------
__device__ __forceinline__ uint32_t rotl32(uint32_t v, uint32_t d) {
  return (v << d) | (v >> (32u - d));
}

__device__ __forceinline__ void threefry2x32(uint32_t k0, uint32_t k1,
                                             uint32_t& x0, uint32_t& x1) {
  uint32_t k2 = k0 ^ k1 ^ 0x1BD11BDAu;
  x0 += k0; x1 += k1;
#define TFR(r) { x0 += x1; x1 = rotl32(x1, r); x1 ^= x0; }
  TFR(13u) TFR(15u) TFR(26u) TFR(6u)
  x0 += k1; x1 += k2 + 1u;
  TFR(17u) TFR(29u) TFR(16u) TFR(24u)
  x0 += k2; x1 += k0 + 2u;
  TFR(13u) TFR(15u) TFR(26u) TFR(6u)
  x0 += k0; x1 += k1 + 3u;
  TFR(17u) TFR(29u) TFR(16u) TFR(24u)
  x0 += k1; x1 += k2 + 4u;
  TFR(13u) TFR(15u) TFR(26u) TFR(6u)
  x0 += k2; x1 += k0 + 5u;
#undef TFR
}

// bits -> N(0,1), matching jax.random.normal f32 path (XLA ErfInv32 / Giles).
__device__ __forceinline__ float bits_to_normal(uint32_t bits) {
  uint32_t fb = (bits >> 9) | 0x3f800000u;
  float f = __uint_as_float(fb) - 1.0f;        // [0, 1)
  const float lo = -0.99999994f;               // nextafter(-1,0) in f32
  float u = f * 2.0f + lo;
  u = fmaxf(lo, u);

  float w = -log1pf(-u * u);
  float p;
  if (w < 5.0f) {
    w = w - 2.5f;
    p = 2.81022636e-08f;
    p = fmaf(p, w, 3.43273939e-07f);
    p = fmaf(p, w, -3.5233877e-06f);
    p = fmaf(p, w, -4.39150654e-06f);
    p = fmaf(p, w, 0.00021858087f);
    p = fmaf(p, w, -0.00125372503f);
    p = fmaf(p, w, -0.00417768164f);
    p = fmaf(p, w, 0.246640727f);
    p = fmaf(p, w, 1.50140941f);
  } else {
    w = sqrtf(w) - 3.0f;
    p = -0.000200214257f;
    p = fmaf(p, w, 0.000100950558f);
    p = fmaf(p, w, 0.00134934322f);
    p = fmaf(p, w, -0.00367342844f);
    p = fmaf(p, w, 0.00573950773f);
    p = fmaf(p, w, -0.0076224613f);
    p = fmaf(p, w, 0.00943887047f);
    p = fmaf(p, w, 1.00167406f);
    p = fmaf(p, w, 2.83297682f);
  }
  return 1.41421356237f * (p * u);
}

// noise for (step t, flat index j): partitionable random_bits
__device__ __forceinline__ float noise_at(int t, int j) {
  uint2 k = g_keys[t];
  uint32_t x0 = 0u, x1 = (uint32_t)j;
  threefry2x32(k.x, k.y, x0, x1);
  return bits_to_normal(x0 ^ x1);
}

// ---------------------------------------------------------------------------
// K0: per-step keys from jax.random.split(key(42), T)  [partitionable fold]
// ---------------------------------------------------------------------------
__global__ void keys_kernel() {
  int t = blockIdx.x * blockDim.x + threadIdx.x;
  if (t >= T_STEPS) return;
  uint32_t x0 = 0u, x1 = (uint32_t)t;
  threefry2x32(0u, 42u, x0, x1);
  g_keys[t] = make_uint2(x0, x1);
}

// ---------------------------------------------------------------------------
// DPP rotation reduction within each 16-lane row (one sim). VALU-latency,
// no LDS. Control codes must be compile-time constants -> template param.
// ---------------------------------------------------------------------------
#if USE_DPP
template <int CTRL>
__device__ __forceinline__ float dpp_movf(float v) {
  return __int_as_float(
      __builtin_amdgcn_update_dpp(0, __float_as_int(v), CTRL, 0xF, 0xF, true));
}
__device__ __forceinline__ void row16_sum_max(float a, float& s, float& m) {
  s = a; m = a;
  s += dpp_movf<0xB1>(s);   m = fmaxf(m, dpp_movf<0xB1>(m));   // quad_perm xor1
  s += dpp_movf<0x4E>(s);   m = fmaxf(m, dpp_movf<0x4E>(m));   // quad_perm xor2
  s += dpp_movf<0x124>(s);  m = fmaxf(m, dpp_movf<0x124>(m));  // row_ror:4
  s += dpp_movf<0x128>(s);  m = fmaxf(m, dpp_movf<0x128>(m));  // row_ror:8
}
#else
__device__ __forceinline__ void row16_sum_max(float a, float& s, float& m) {
  s = a; m = a;
#pragma unroll
  for (int msk = 1; msk <= 8; msk <<= 1) {
    s += __shfl_xor(s, msk, 16);
    m = fmaxf(m, __shfl_xor(m, msk, 16));
  }
}
#endif

// ---------------------------------------------------------------------------
// KB: sequential LCA dynamics, noise generated inline (one step ahead, off
// the dependency chain). Writes only the active prefix, coalesced [t][j].
// ---------------------------------------------------------------------------
__global__ __launch_bounds__(64) void sim_kernel(const float* __restrict__ ff) {
  const int j = blockIdx.x * 64 + threadIdx.x;     // s = j>>4, d = j&15
  const float ffv = ff[j];

  float pre = 0.0f, act = 0.0f;
  int tfreeze = T_STEPS;

  float n_cur = noise_at(0, j);
  for (int t = 0; t < T_STEPS; ++t) {
    float s, m;
    row16_sum_max(act, s, m);
    if (!(m < 1.0f)) { tfreeze = t; break; }
    float n_next = 0.0f;
    if (t + 1 < T_STEPS) n_next = noise_at(t + 1, j);   // independent of state
    float expr = ffv - 0.1f * pre - 0.1f * (s - act);
    pre = pre + expr * 0.01f;
    pre = pre + n_cur * 0.03162277660168379f;           // + dw * sqrt(0.001)
    act = fmaxf(pre, 0.0f);
    g_ws_pre[(size_t)t * NJ + j] = pre;
    n_cur = n_next;
  }
  if ((j & 15) == 0) g_tf[j >> 4] = tfreeze;            // tfreeze >= 1 always
}

// ---------------------------------------------------------------------------
// KC: coalesced output fill. One block per (s,d) row; threads stride t.
// out_pre[j][idx] = ws[min(idx-1, tf-1)][j]; out_act = relu(same).
// ---------------------------------------------------------------------------
__global__ __launch_bounds__(256) void fill_kernel(float* __restrict__ out) {
  const int j = blockIdx.x;
  const int tf = g_tf[j >> 4];
  float* __restrict__ pre_out = out + (size_t)j * ROW;
  float* __restrict__ act_out = out + HALF_OUT + (size_t)j * ROW;

  for (int idx = threadIdx.x; idx < ROW; idx += 256) {
    float v;
    if (idx == 0) {
      v = 0.0f;
    } else {
      int te = idx - 1;
      if (te > tf - 1) te = tf - 1;
      v = g_ws_pre[(size_t)te * NJ + j];
    }
    pre_out[idx] = v;
    act_out[idx] = fmaxf(v, 0.0f);
  }
}

// ---------------------------------------------------------------------------
extern "C" void kernel_launch(void* const* d_in, const int* in_sizes, int n_in,
                              void* d_out, int out_size, void* d_ws, size_t ws_size,
                              hipStream_t stream) {
  const float* ff = (const float*)d_in[0];
  float* out = (float*)d_out;

  keys_kernel<<<dim3((T_STEPS + 255) / 256), dim3(256), 0, stream>>>();
  sim_kernel<<<dim3(NJ / 64), dim3(64), 0, stream>>>(ff);
  fill_kernel<<<dim3(NJ), dim3(256), 0, stream>>>(out);
}

// Round 5
// 187.305 us; speedup vs baseline: 3.5265x; 1.8297x over previous
//
#include <hip/hip_runtime.h>
#include <cstdint>

// LCA model constants
#define T_STEPS 3000
#define S_SIMS  1000
#define D_DIM   16
#define NJ      (S_SIMS * D_DIM)          // 16000 elements per step
#define ROW     (T_STEPS + 1)             // 3001 outputs per (s,d)
#define HALF_OUT ((long long)NJ * ROW)    // 48,016,000 floats per output tensor

#define NPROD 7                           // producer waves per block
#define DEPTH 16                          // LDS ring slots (steps)

__device__ uint2  g_keys[T_STEPS];
__device__ int    g_tf[S_SIMS];
__device__ float  g_ws_pre[(size_t)T_STEPS * NJ];   // [t][j], prefix only

// ---------------------------------------------------------------------------
// Threefry-2x32 (20 rounds), bit-exact vs jax._src.prng (partitionable mode)
// ---------------------------------------------------------------------------
__device__ __forceinline__ uint32_t rotl32(uint32_t v, uint32_t d) {
  return (v << d) | (v >> (32u - d));
}

__device__ __forceinline__ void threefry2x32(uint32_t k0, uint32_t k1,
                                             uint32_t& x0, uint32_t& x1) {
  uint32_t k2 = k0 ^ k1 ^ 0x1BD11BDAu;
  x0 += k0; x1 += k1;
#define TFR(r) { x0 += x1; x1 = rotl32(x1, r); x1 ^= x0; }
  TFR(13u) TFR(15u) TFR(26u) TFR(6u)
  x0 += k1; x1 += k2 + 1u;
  TFR(17u) TFR(29u) TFR(16u) TFR(24u)
  x0 += k2; x1 += k0 + 2u;
  TFR(13u) TFR(15u) TFR(26u) TFR(6u)
  x0 += k0; x1 += k1 + 3u;
  TFR(17u) TFR(29u) TFR(16u) TFR(24u)
  x0 += k1; x1 += k2 + 4u;
  TFR(13u) TFR(15u) TFR(26u) TFR(6u)
  x0 += k2; x1 += k0 + 5u;
#undef TFR
}

// bits -> N(0,1), matching jax.random.normal f32 path (XLA ErfInv32 / Giles).
__device__ __forceinline__ float bits_to_normal(uint32_t bits) {
  uint32_t fb = (bits >> 9) | 0x3f800000u;
  float f = __uint_as_float(fb) - 1.0f;        // [0, 1)
  const float lo = -0.99999994f;               // nextafter(-1,0) in f32
  float u = f * 2.0f + lo;
  u = fmaxf(lo, u);

  float w = -log1pf(-u * u);
  float p;
  if (w < 5.0f) {
    w = w - 2.5f;
    p = 2.81022636e-08f;
    p = fmaf(p, w, 3.43273939e-07f);
    p = fmaf(p, w, -3.5233877e-06f);
    p = fmaf(p, w, -4.39150654e-06f);
    p = fmaf(p, w, 0.00021858087f);
    p = fmaf(p, w, -0.00125372503f);
    p = fmaf(p, w, -0.00417768164f);
    p = fmaf(p, w, 0.246640727f);
    p = fmaf(p, w, 1.50140941f);
  } else {
    w = sqrtf(w) - 3.0f;
    p = -0.000200214257f;
    p = fmaf(p, w, 0.000100950558f);
    p = fmaf(p, w, 0.00134934322f);
    p = fmaf(p, w, -0.00367342844f);
    p = fmaf(p, w, 0.00573950773f);
    p = fmaf(p, w, -0.0076224613f);
    p = fmaf(p, w, 0.00943887047f);
    p = fmaf(p, w, 1.00167406f);
    p = fmaf(p, w, 2.83297682f);
  }
  return 1.41421356237f * (p * u);
}

// noise for (step t, flat index j): partitionable random_bits
__device__ __forceinline__ float noise_at(int t, int j) {
  uint2 k = g_keys[t];
  uint32_t x0 = 0u, x1 = (uint32_t)j;
  threefry2x32(k.x, k.y, x0, x1);
  return bits_to_normal(x0 ^ x1);
}

// ---------------------------------------------------------------------------
// K0: per-step keys from jax.random.split(key(42), T)  [partitionable fold]
// ---------------------------------------------------------------------------
__global__ void keys_kernel() {
  int t = blockIdx.x * blockDim.x + threadIdx.x;
  if (t >= T_STEPS) return;
  uint32_t x0 = 0u, x1 = (uint32_t)t;
  threefry2x32(0u, 42u, x0, x1);
  g_keys[t] = make_uint2(x0, x1);
}

// ---------------------------------------------------------------------------
// DPP rotation reduction within each 16-lane row (one sim). VALU-latency.
// ---------------------------------------------------------------------------
template <int CTRL>
__device__ __forceinline__ float dpp_movf(float v) {
  return __int_as_float(
      __builtin_amdgcn_update_dpp(0, __float_as_int(v), CTRL, 0xF, 0xF, true));
}
__device__ __forceinline__ void row16_sum_max(float a, float& s, float& m) {
  s = a; m = a;
  s += dpp_movf<0xB1>(s);   m = fmaxf(m, dpp_movf<0xB1>(m));   // quad_perm xor1
  s += dpp_movf<0x4E>(s);   m = fmaxf(m, dpp_movf<0x4E>(m));   // quad_perm xor2
  s += dpp_movf<0x124>(s);  m = fmaxf(m, dpp_movf<0x124>(m));  // row_ror:4
  s += dpp_movf<0x128>(s);  m = fmaxf(m, dpp_movf<0x128>(m));  // row_ror:8
}

// ---------------------------------------------------------------------------
// KB: producer-consumer sim. Wave 0 = dynamics (4 sims); waves 1..7 produce
// noise for steps t ≡ p (mod 7) into a DEPTH-slot LDS ring. Barrier-free
// sync via volatile LDS counters + s_sleep spins.
// ---------------------------------------------------------------------------
__global__ __launch_bounds__(512) void sim_kernel(const float* __restrict__ ff) {
  __shared__ float sh_nbuf[DEPTH][64];
  __shared__ volatile unsigned sh_prodc[NPROD];  // per-producer completed count
  __shared__ volatile unsigned sh_cons;          // consumer published t+1
  __shared__ volatile unsigned sh_done;

  const int lane = threadIdx.x & 63;
  const int wid  = threadIdx.x >> 6;
  const int j    = blockIdx.x * 64 + lane;       // s = j>>4, d = j&15

  if (threadIdx.x < NPROD) sh_prodc[threadIdx.x] = 0u;
  if (threadIdx.x == 0) { sh_cons = 0u; sh_done = 0u; }
  __syncthreads();

  if (wid == 0) {
    // ----------------- consumer: LCA dynamics -----------------
    const float ffv = ff[j];
    float pre = 0.0f, act = 0.0f;
    bool frozen = false;
    int my_tf = T_STEPS;
    unsigned Rc = 0;   // steps < Rc are known produced

#define ENSURE(x)                                                     \
    while (Rc <= (unsigned)(x)) {                                     \
      unsigned mn = 0xffffffffu;                                      \
      for (int p_ = 0; p_ < NPROD; ++p_) {                            \
        unsigned lim = (unsigned)p_ + (unsigned)NPROD * sh_prodc[p_]; \
        if (lim < mn) mn = lim;                                       \
      }                                                               \
      Rc = mn;                                                        \
      if (Rc <= (unsigned)(x)) __builtin_amdgcn_s_sleep(2);           \
    }

    float n0 = 0.0f, n1 = 0.0f;
    {
      ENSURE(1);
      n0 = sh_nbuf[0][lane];
      n1 = sh_nbuf[1][lane];
      asm volatile("s_waitcnt lgkmcnt(0)" ::: "memory");
    }

    int t = 0;
    while (true) {
      // free slot t (n0 in reg), protect t+1..t+15
      if (lane == 0) sh_cons = (unsigned)(t + 1);
      // prefetch noise for t+2, t+3 (off the chain)
      int xe = (t + 3 < T_STEPS) ? (t + 3) : ((t + 2 < T_STEPS) ? (t + 2) : -1);
      if (xe >= 0) { ENSURE(xe); }
      float n2 = 0.0f, n3 = 0.0f;
      if (t + 2 < T_STEPS) n2 = sh_nbuf[(t + 2) & (DEPTH - 1)][lane];
      if (t + 3 < T_STEPS) n3 = sh_nbuf[(t + 3) & (DEPTH - 1)][lane];

      // ---- step t (noise n0) ----
      {
        float s, m; row16_sum_max(act, s, m);
        if (!frozen && !(m < 1.0f)) { frozen = true; my_tf = t; }
        if (__all(frozen)) break;
        if (!frozen) {
          float expr = ffv - 0.1f * pre - 0.1f * (s - act);
          pre = pre + expr * 0.01f;
          pre = pre + n0 * 0.03162277660168379f;   // + dw * sqrt(0.001)
          act = fmaxf(pre, 0.0f);
          g_ws_pre[(size_t)t * NJ + j] = pre;
        }
      }
      ++t; if (t == T_STEPS) break;

      // ---- step t (noise n1) ----
      {
        float s, m; row16_sum_max(act, s, m);
        if (!frozen && !(m < 1.0f)) { frozen = true; my_tf = t; }
        if (__all(frozen)) break;
        if (!frozen) {
          float expr = ffv - 0.1f * pre - 0.1f * (s - act);
          pre = pre + expr * 0.01f;
          pre = pre + n1 * 0.03162277660168379f;
          act = fmaxf(pre, 0.0f);
          g_ws_pre[(size_t)t * NJ + j] = pre;
        }
      }
      ++t; if (t == T_STEPS) break;

      asm volatile("s_waitcnt lgkmcnt(0)" ::: "memory");  // n2/n3 landed
      n0 = n2; n1 = n3;
    }
#undef ENSURE
    asm volatile("s_waitcnt lgkmcnt(0)" ::: "memory");
    if (threadIdx.x == 0) sh_done = 1u;
    if ((lane & 15) == 0) g_tf[j >> 4] = my_tf;   // uniform within 16-lane row
  } else {
    // ----------------- producers: noise for t ≡ p (mod NPROD) -----------------
    const int p = wid - 1;
    unsigned count = 0;
    for (int t = p; t < T_STEPS; t += NPROD) {
      float n = noise_at(t, j);                   // expensive, computed first
      if (t >= DEPTH) {
        bool quit = false;
        while (true) {
          if (sh_done) { quit = true; break; }
          unsigned pc = sh_cons;
          if ((unsigned)t <= pc + (DEPTH - 1)) break;   // slot free
          __builtin_amdgcn_s_sleep(8);
        }
        if (quit) break;
      }
      sh_nbuf[t & (DEPTH - 1)][lane] = n;
      asm volatile("s_waitcnt lgkmcnt(0)" ::: "memory");  // data before counter
      ++count;
      if (lane == 0) sh_prodc[p] = count;
    }
  }
}

// ---------------------------------------------------------------------------
// KC: coalesced output fill. One block per (s,d) row; threads stride t.
// ---------------------------------------------------------------------------
__global__ __launch_bounds__(256) void fill_kernel(float* __restrict__ out) {
  const int j = blockIdx.x;
  const int tf = g_tf[j >> 4];
  float* __restrict__ pre_out = out + (size_t)j * ROW;
  float* __restrict__ act_out = out + HALF_OUT + (size_t)j * ROW;

  for (int idx = threadIdx.x; idx < ROW; idx += 256) {
    float v;
    if (idx == 0) {
      v = 0.0f;
    } else {
      int te = idx - 1;
      if (te > tf - 1) te = tf - 1;
      v = g_ws_pre[(size_t)te * NJ + j];
    }
    pre_out[idx] = v;
    act_out[idx] = fmaxf(v, 0.0f);
  }
}

// ---------------------------------------------------------------------------
extern "C" void kernel_launch(void* const* d_in, const int* in_sizes, int n_in,
                              void* d_out, int out_size, void* d_ws, size_t ws_size,
                              hipStream_t stream) {
  const float* ff = (const float*)d_in[0];
  float* out = (float*)d_out;

  keys_kernel<<<dim3((T_STEPS + 255) / 256), dim3(256), 0, stream>>>();
  sim_kernel<<<dim3(NJ / 64), dim3(512), 0, stream>>>(ff);
  fill_kernel<<<dim3(NJ), dim3(256), 0, stream>>>(out);
}

// Round 6
// 133.161 us; speedup vs baseline: 4.9605x; 1.4066x over previous
//
#include <hip/hip_runtime.h>
#include <cstdint>

// LCA model constants
#define T_STEPS 3000
#define S_SIMS  1000
#define D_DIM   16
#define NJ      (S_SIMS * D_DIM)          // 16000 elements per step
#define ROW     (T_STEPS + 1)             // 3001 outputs per (s,d)
#define HALF_OUT ((long long)NJ * ROW)    // 48,016,000 floats per output tensor

#define NPROD 7                           // producer waves per block
#define DEPTH 32                          // LDS ring slots (steps), power of 2
#define BATCH 8                           // consumer speculation batch
#define SQSTEP 0.03162277660168379f       // sqrt(0.001)

__device__ uint2  g_keys[T_STEPS];
__device__ int    g_tf[S_SIMS];
__device__ float  g_ws_pre[(size_t)T_STEPS * NJ];   // [t][j], prefix only

// ---------------------------------------------------------------------------
// Threefry-2x32 (20 rounds), bit-exact vs jax._src.prng (partitionable mode)
// ---------------------------------------------------------------------------
__device__ __forceinline__ uint32_t rotl32(uint32_t v, uint32_t d) {
  return (v << d) | (v >> (32u - d));
}

__device__ __forceinline__ void threefry2x32(uint32_t k0, uint32_t k1,
                                             uint32_t& x0, uint32_t& x1) {
  uint32_t k2 = k0 ^ k1 ^ 0x1BD11BDAu;
  x0 += k0; x1 += k1;
#define TFR(r) { x0 += x1; x1 = rotl32(x1, r); x1 ^= x0; }
  TFR(13u) TFR(15u) TFR(26u) TFR(6u)
  x0 += k1; x1 += k2 + 1u;
  TFR(17u) TFR(29u) TFR(16u) TFR(24u)
  x0 += k2; x1 += k0 + 2u;
  TFR(13u) TFR(15u) TFR(26u) TFR(6u)
  x0 += k0; x1 += k1 + 3u;
  TFR(17u) TFR(29u) TFR(16u) TFR(24u)
  x0 += k1; x1 += k2 + 4u;
  TFR(13u) TFR(15u) TFR(26u) TFR(6u)
  x0 += k2; x1 += k0 + 5u;
#undef TFR
}

// bits -> N(0,1), matching jax.random.normal f32 path (XLA ErfInv32 / Giles).
// log1p(-u*u) computed via hardware log2: log(1-u^2) = ln2*log2((1-u)(1+u)).
// (1-u) is exact near u~1 (Sterbenz), so no cancellation; few-ulp deviation
// from OCML log1pf is far below the 0.1325 output tolerance.
__device__ __forceinline__ float bits_to_normal(uint32_t bits) {
  uint32_t fb = (bits >> 9) | 0x3f800000u;
  float f = __uint_as_float(fb) - 1.0f;        // [0, 1)
  const float lo = -0.99999994f;               // nextafter(-1,0) in f32
  float u = f * 2.0f + lo;                     // exact: *2.0 is power-of-2
  u = fmaxf(lo, u);

  float w = -0.6931471805599453f * __log2f((1.0f - u) * (1.0f + u));
  float p;
  if (w < 5.0f) {
    w = w - 2.5f;
    p = 2.81022636e-08f;
    p = fmaf(p, w, 3.43273939e-07f);
    p = fmaf(p, w, -3.5233877e-06f);
    p = fmaf(p, w, -4.39150654e-06f);
    p = fmaf(p, w, 0.00021858087f);
    p = fmaf(p, w, -0.00125372503f);
    p = fmaf(p, w, -0.00417768164f);
    p = fmaf(p, w, 0.246640727f);
    p = fmaf(p, w, 1.50140941f);
  } else {
    w = sqrtf(w) - 3.0f;
    p = -0.000200214257f;
    p = fmaf(p, w, 0.000100950558f);
    p = fmaf(p, w, 0.00134934322f);
    p = fmaf(p, w, -0.00367342844f);
    p = fmaf(p, w, 0.00573950773f);
    p = fmaf(p, w, -0.0076224613f);
    p = fmaf(p, w, 0.00943887047f);
    p = fmaf(p, w, 1.00167406f);
    p = fmaf(p, w, 2.83297682f);
  }
  return 1.41421356237f * (p * u);
}

// noise for (step t, flat index j): partitionable random_bits
__device__ __forceinline__ float noise_at(int t, int j) {
  uint2 k = g_keys[t];
  uint32_t x0 = 0u, x1 = (uint32_t)j;
  threefry2x32(k.x, k.y, x0, x1);
  return bits_to_normal(x0 ^ x1);
}

// ---------------------------------------------------------------------------
// K0: per-step keys from jax.random.split(key(42), T)  [partitionable fold]
// ---------------------------------------------------------------------------
__global__ void keys_kernel() {
  int t = blockIdx.x * blockDim.x + threadIdx.x;
  if (t >= T_STEPS) return;
  uint32_t x0 = 0u, x1 = (uint32_t)t;
  threefry2x32(0u, 42u, x0, x1);
  g_keys[t] = make_uint2(x0, x1);
}

// ---------------------------------------------------------------------------
// DPP reductions within each 16-lane row (one sim). old=0 + full masks +
// bound_ctrl => fusible into v_add_f32_dpp by GCNDPPCombine.
// ---------------------------------------------------------------------------
template <int CTRL>
__device__ __forceinline__ float dpp_movf(float v) {
  return __int_as_float(
      __builtin_amdgcn_update_dpp(0, __float_as_int(v), CTRL, 0xF, 0xF, true));
}
__device__ __forceinline__ float row16_sum(float a) {
  float s = a;
  s += dpp_movf<0xB1>(s);    // quad_perm xor1
  s += dpp_movf<0x4E>(s);    // quad_perm xor2
  s += dpp_movf<0x124>(s);   // row_ror:4
  s += dpp_movf<0x128>(s);   // row_ror:8
  return s;
}
__device__ __forceinline__ float row16_max(float a) {  // valid for a >= 0
  float m = a;
  m = fmaxf(m, dpp_movf<0xB1>(m));
  m = fmaxf(m, dpp_movf<0x4E>(m));
  m = fmaxf(m, dpp_movf<0x124>(m));
  m = fmaxf(m, dpp_movf<0x128>(m));
  return m;
}

// ---------------------------------------------------------------------------
// KB: producer-consumer sim with batch-8 speculative consumer.
// Wave 0 = dynamics (4 sims); waves 1..7 produce noise for t ≡ p (mod 7)
// into a DEPTH-slot LDS ring. Speculation past a threshold crossing is
// harmless: fill reads only ws[<= tf-1]; crossed sims are killed via
// pre = -1e30 so relu(act)=0 forever (no per-step masking, no retrigger).
// ---------------------------------------------------------------------------
__global__ __launch_bounds__(512) void sim_kernel(const float* __restrict__ ff) {
  __shared__ float sh_nbuf[DEPTH][64];
  __shared__ volatile unsigned sh_prodc[NPROD];  // per-producer completed count
  __shared__ volatile unsigned sh_cons;          // consumer watermark (freed < this+BATCH)
  __shared__ volatile unsigned sh_done;

  const int lane = threadIdx.x & 63;
  const int wid  = threadIdx.x >> 6;
  const int j    = blockIdx.x * 64 + lane;       // s = j>>4, d = j&15

  if (threadIdx.x < NPROD) sh_prodc[threadIdx.x] = 0u;
  if (threadIdx.x == 0) { sh_cons = 0u; sh_done = 0u; }
  __syncthreads();

  if (wid == 0) {
    // ----------------- consumer: LCA dynamics, batch-8 speculative -----------------
    const float ffv = ff[j];
    float pre = 0.0f, act = 0.0f;
    bool dead = false;
    int my_tf = T_STEPS;
    unsigned Rc = 0;   // steps < Rc are known produced

#define ENSURE(x)                                                     \
    while (Rc <= (unsigned)(x)) {                                     \
      unsigned mn = 0xffffffffu;                                      \
      for (int p_ = 0; p_ < NPROD; ++p_) {                            \
        unsigned lim = (unsigned)p_ + (unsigned)NPROD * sh_prodc[p_]; \
        if (lim < mn) mn = lim;                                       \
      }                                                               \
      Rc = mn;                                                        \
      if (Rc <= (unsigned)(x)) __builtin_amdgcn_s_sleep(2);           \
    }

    float n[BATCH], nn[BATCH], a[BATCH];
    ENSURE(BATCH - 1);
#pragma unroll
    for (int k = 0; k < BATCH; ++k) n[k] = sh_nbuf[k][lane];

    int t0 = 0;
    while (true) {
      // free slots < t0+BATCH (their values are in n[]); prefetch next batch
      if (lane == 0) sh_cons = (unsigned)(t0 + BATCH);
      const bool more = (t0 + BATCH < T_STEPS);
      if (more) {
        ENSURE(t0 + 2 * BATCH - 1);
#pragma unroll
        for (int k = 0; k < BATCH; ++k)
          nn[k] = sh_nbuf[(t0 + BATCH + k) & (DEPTH - 1)][lane];
      }

      // ---- speculative batch: 8 unconditional steps ----
      float bmax = 0.0f;
      float* __restrict__ wsp = &g_ws_pre[(size_t)t0 * NJ + j];
#pragma unroll
      for (int k = 0; k < BATCH; ++k) {
        float s  = row16_sum(act);
        float q  = s - act;                       // sum of other units
        float e1 = fmaf(-0.1f, pre, ffv);         // ff - leak*pre
        float e2 = fmaf(-0.1f, q, e1);            // - competition
        pre = fmaf(e2, 0.01f, pre);               // + expr*dt
        pre = fmaf(n[k], SQSTEP, pre);            // + dw*sqrt(0.001)
        act = fmaxf(pre, 0.0f);
        a[k] = act;
        bmax = fmaxf(bmax, act);
        wsp[(size_t)k * NJ] = pre;
      }

      // ---- freeze detection, once per batch (rare trigger: <=4 per wave) ----
      if (__any(bmax >= 1.0f)) {
        bool found = dead;
#pragma unroll
        for (int k = 0; k < BATCH; ++k) {
          float m = row16_max(a[k]);              // row-uniform
          if (!found && m >= 1.0f) { found = true; my_tf = t0 + k + 1; }
        }
        if (found && !dead) {                     // this row just crossed
          dead = true;
          pre = -1e30f;                           // act = relu(pre) = 0 forever
          act = 0.0f;
        }
        if (__all(dead)) break;
      }

      if (!more) break;
#pragma unroll
      for (int k = 0; k < BATCH; ++k) n[k] = nn[k];
      t0 += BATCH;
    }
#undef ENSURE
    if ((lane & 15) == 0) g_tf[j >> 4] = my_tf;   // uniform within 16-lane row
    if (threadIdx.x == 0) sh_done = 1u;
  } else {
    // ----------------- producers: noise for t ≡ p (mod NPROD) -----------------
    const int p = wid - 1;
    unsigned count = 0;
    for (int t = p; t < T_STEPS; t += NPROD) {
      float n = noise_at(t, j);                   // expensive, computed first
      if (t >= DEPTH) {
        bool quit = false;
        while (true) {
          if (sh_done) { quit = true; break; }
          unsigned pc = sh_cons;                  // slots < pc+BATCH are free
          if ((unsigned)t <= pc + (DEPTH - 1)) break;
          __builtin_amdgcn_s_sleep(8);
        }
        if (quit) break;
      }
      sh_nbuf[t & (DEPTH - 1)][lane] = n;
      asm volatile("s_waitcnt lgkmcnt(0)" ::: "memory");  // data before counter
      ++count;
      if (lane == 0) sh_prodc[p] = count;
    }
  }
}

// ---------------------------------------------------------------------------
// KC: coalesced output fill. One block per (s,d) row; threads stride t.
// ---------------------------------------------------------------------------
__global__ __launch_bounds__(256) void fill_kernel(float* __restrict__ out) {
  const int j = blockIdx.x;
  const int tf = g_tf[j >> 4];
  float* __restrict__ pre_out = out + (size_t)j * ROW;
  float* __restrict__ act_out = out + HALF_OUT + (size_t)j * ROW;

  for (int idx = threadIdx.x; idx < ROW; idx += 256) {
    float v;
    if (idx == 0) {
      v = 0.0f;
    } else {
      int te = idx - 1;
      if (te > tf - 1) te = tf - 1;
      v = g_ws_pre[(size_t)te * NJ + j];
    }
    pre_out[idx] = v;
    act_out[idx] = fmaxf(v, 0.0f);
  }
}

// ---------------------------------------------------------------------------
extern "C" void kernel_launch(void* const* d_in, const int* in_sizes, int n_in,
                              void* d_out, int out_size, void* d_ws, size_t ws_size,
                              hipStream_t stream) {
  const float* ff = (const float*)d_in[0];
  float* out = (float*)d_out;

  keys_kernel<<<dim3((T_STEPS + 255) / 256), dim3(256), 0, stream>>>();
  sim_kernel<<<dim3(NJ / 64), dim3(512), 0, stream>>>(ff);
  fill_kernel<<<dim3(NJ), dim3(256), 0, stream>>>(out);
}